// Round 9
// baseline (259.509 us; speedup 1.0000x reference)
//
#include <hip/hip_runtime.h>
#include <hip/hip_bf16.h>

// Problem constants (reference: B=2, N=2048, DIM=1024, INTER=1024, HEAD=16, N_SEG=4)
#define BB 2
#define NN 2048
#define DIM 1024
#define INTER 1024
#define NHEAD 16
#define HDIM 64          // INTER / NHEAD
#define NSEG 4
#define QKVW (3 * INTER) // 3072

typedef __attribute__((ext_vector_type(8))) short bf16x8;
typedef __attribute__((ext_vector_type(4))) float f32x4;

static __device__ __forceinline__ unsigned short f2bf(float f) {
    __hip_bfloat16 h = __float2bfloat16(f);   // RNE
    return *reinterpret_cast<unsigned short*>(&h);
}
static __device__ __forceinline__ float bf2f(unsigned short u) {
    unsigned int x = ((unsigned int)u) << 16;
    return __builtin_bit_cast(float, x);
}
// Round-half-up bf16 pack: u+0x8000 then take hi16 of each via one v_perm.
// (v_cvt_pk_bf16_f32 was tried round 1: wrong semantics -> 6e-3 error.)
static __device__ __forceinline__ unsigned int pack_bf16_rn(float lo, float hi) {
    unsigned int u = __builtin_bit_cast(unsigned int, lo) + 0x8000u;
    unsigned int v = __builtin_bit_cast(unsigned int, hi) + 0x8000u;
    return __builtin_amdgcn_perm(v, u, 0x07060302u);
}

// ---------------------------------------------------------------------------
// Fused prepass (single launch):
//   blocks [0,4096)        : features fp32 -> bf16
//   blocks [4096,6144)     : mask int32 -> byte-packed
//   blocks [6144,6912)     : W_qkv  [1024][3072] fp32 -> wqt [3072][1024] bf16
//   blocks [6912,7168)     : W_out  [1024][1024] fp32 -> woh/wol hi/lo transposed
// ---------------------------------------------------------------------------
__global__ __launch_bounds__(256) void prep_fused(
        const float* __restrict__ features, unsigned short* __restrict__ featb,
        const int* __restrict__ mask, unsigned char* __restrict__ maskb,
        const float* __restrict__ W_qkv, unsigned short* __restrict__ wqt,
        const float* __restrict__ W_out, unsigned short* __restrict__ woh,
        unsigned short* __restrict__ wol) {
    __shared__ float tile[64][65];
    const int bid = blockIdx.x;
    const int t = threadIdx.x;

    if (bid < 4096) {                                   // ---- conv f32->bf16
        int i = (bid * 256 + t) * 4;
        float4 v = *(const float4*)&features[i];
        ushort4 o = {f2bf(v.x), f2bf(v.y), f2bf(v.z), f2bf(v.w)};
        *(ushort4*)&featb[i] = o;
        return;
    }
    if (bid < 6144) {                                   // ---- mask pack
        size_t i = (size_t)((bid - 4096) * 256 + t) * 16;
        int4 a = *(const int4*)&mask[i];
        int4 b = *(const int4*)&mask[i + 4];
        int4 c = *(const int4*)&mask[i + 8];
        int4 d = *(const int4*)&mask[i + 12];
        uint4 p;
        p.x = (unsigned)(a.x & 3) | ((unsigned)(a.y & 3) << 8) | ((unsigned)(a.z & 3) << 16) | ((unsigned)(a.w & 3) << 24);
        p.y = (unsigned)(b.x & 3) | ((unsigned)(b.y & 3) << 8) | ((unsigned)(b.z & 3) << 16) | ((unsigned)(b.w & 3) << 24);
        p.z = (unsigned)(c.x & 3) | ((unsigned)(c.y & 3) << 8) | ((unsigned)(c.z & 3) << 16) | ((unsigned)(c.w & 3) << 24);
        p.w = (unsigned)(d.x & 3) | ((unsigned)(d.y & 3) << 8) | ((unsigned)(d.z & 3) << 16) | ((unsigned)(d.w & 3) << 24);
        *(uint4*)&maskb[i] = p;
        return;
    }
    if (bid < 6912) {                                   // ---- transpose W_qkv
        const int id = bid - 6144;
        const int c0 = (id % 48) * 64, r0 = (id / 48) * 64;
        const int R = DIM, C = QKVW;
#pragma unroll
        for (int it = 0; it < 4; ++it) {
            int r = it * 16 + (t >> 4);
            int c = (t & 15) * 4;
            float4 v = *(const float4*)&W_qkv[(size_t)(r0 + r) * C + c0 + c];
            tile[r][c] = v.x; tile[r][c + 1] = v.y; tile[r][c + 2] = v.z; tile[r][c + 3] = v.w;
        }
        __syncthreads();
#pragma unroll
        for (int it = 0; it < 4; ++it) {
            int c = it * 16 + (t >> 4);
            int r = (t & 15) * 4;
            ushort4 o = {f2bf(tile[r][c]), f2bf(tile[r + 1][c]), f2bf(tile[r + 2][c]), f2bf(tile[r + 3][c])};
            *(ushort4*)&wqt[(size_t)(c0 + c) * R + r0 + r] = o;
        }
        return;
    }
    {                                                   // ---- W_out split-transpose
        const int id = bid - 6912;
        const int c0 = (id % 16) * 64, r0 = (id / 16) * 64;
        const int R = INTER, C = DIM;
#pragma unroll
        for (int it = 0; it < 4; ++it) {
            int r = it * 16 + (t >> 4);
            int c = (t & 15) * 4;
            float4 v = *(const float4*)&W_out[(size_t)(r0 + r) * C + c0 + c];
            tile[r][c] = v.x; tile[r][c + 1] = v.y; tile[r][c + 2] = v.z; tile[r][c + 3] = v.w;
        }
        __syncthreads();
#pragma unroll
        for (int it = 0; it < 4; ++it) {
            int c = it * 16 + (t >> 4);
            int r = (t & 15) * 4;
            float v0 = tile[r][c], v1 = tile[r + 1][c], v2 = tile[r + 2][c], v3 = tile[r + 3][c];
            ushort4 hh, ll;
            hh.x = f2bf(v0); ll.x = f2bf(v0 - bf2f(hh.x));
            hh.y = f2bf(v1); ll.y = f2bf(v1 - bf2f(hh.y));
            hh.z = f2bf(v2); ll.z = f2bf(v2 - bf2f(hh.z));
            hh.w = f2bf(v3); ll.w = f2bf(v3 - bf2f(hh.w));
            *(ushort4*)&woh[(size_t)(c0 + c) * R + r0 + r] = hh;
            *(ushort4*)&wol[(size_t)(c0 + c) * R + r0 + r] = ll;
        }
    }
}

// ---------------------------------------------------------------------------
// QKV GEMM, bf16 MFMA (m97 structure): [4096][1024] @ [3072][1024]^T.
// q pre-scaled by log2e/32 so attention's exp path is a bare exp2.
// ---------------------------------------------------------------------------
#define GBK 32

__global__ __launch_bounds__(256) void gemm_qkv_mfma(
        const unsigned short* __restrict__ A,    // [4096][1024] bf16
        const unsigned short* __restrict__ Bt,   // [3072][1024] bf16
        unsigned short* __restrict__ Cqk,        // [4096][2048] bf16 (q|k)
        unsigned short* __restrict__ Vtg) {      // [2][1024][2048] bf16
    const int K = 1024;
    __shared__ __align__(16) unsigned short As[128][GBK];
    __shared__ __align__(16) unsigned short Bs[128][GBK];
    const int t = threadIdx.x;
    const int w = t >> 6, lane = t & 63, l15 = lane & 15, quad = lane >> 4;
    const int wr = w >> 1, wc = w & 1;
    const int row0 = blockIdx.y * 128, col0 = blockIdx.x * 128;
    const int lrow = lane >> 2;
    const int lkof = (lane & 3) * 8;

    f32x4 acc[4][4];
#pragma unroll
    for (int i = 0; i < 4; ++i)
#pragma unroll
        for (int j = 0; j < 4; ++j) acc[i][j] = (f32x4){0.f, 0.f, 0.f, 0.f};

    for (int k0 = 0; k0 < K; k0 += GBK) {
#pragma unroll
        for (int c = 0; c < 2; ++c) {
            int rbase = w * 32 + c * 16;
            const unsigned short* ga = A  + (size_t)(row0 + rbase + lrow) * K + k0 + lkof;
            const unsigned short* gb = Bt + (size_t)(col0 + rbase + lrow) * K + k0 + lkof;
            __builtin_amdgcn_global_load_lds(
                (const __attribute__((address_space(1))) void*)ga,
                (__attribute__((address_space(3))) void*)&As[rbase][0], 16, 0, 0);
            __builtin_amdgcn_global_load_lds(
                (const __attribute__((address_space(1))) void*)gb,
                (__attribute__((address_space(3))) void*)&Bs[rbase][0], 16, 0, 0);
        }
        __syncthreads();
        bf16x8 af[4], bfr[4];
#pragma unroll
        for (int i = 0; i < 4; ++i) af[i]  = *(const bf16x8*)&As[wr * 64 + i * 16 + l15][quad * 8];
#pragma unroll
        for (int j = 0; j < 4; ++j) bfr[j] = *(const bf16x8*)&Bs[wc * 64 + j * 16 + l15][quad * 8];
#pragma unroll
        for (int i = 0; i < 4; ++i)
#pragma unroll
            for (int j = 0; j < 4; ++j)
                acc[i][j] = __builtin_amdgcn_mfma_f32_16x16x32_bf16(af[i], bfr[j], acc[i][j], 0, 0, 0);
        __syncthreads();
    }

    if (col0 < 2048) {
        const float qs = (col0 < 1024) ? 0.04508422f : 1.0f;   // log2e/32 on q
#pragma unroll
        for (int i = 0; i < 4; ++i)
#pragma unroll
            for (int j = 0; j < 4; ++j)
#pragma unroll
                for (int r = 0; r < 4; ++r) {
                    int row = row0 + wr * 64 + i * 16 + quad * 4 + r;
                    int col = col0 + wc * 64 + j * 16 + l15;
                    Cqk[(size_t)row * 2048 + col] = f2bf(acc[i][j][r] * qs);
                }
    } else {
#pragma unroll
        for (int i = 0; i < 4; ++i)
#pragma unroll
            for (int j = 0; j < 4; ++j) {
                int col = col0 + wc * 64 + j * 16 + l15 - 2048;   // h*64+d
                int row = row0 + wr * 64 + i * 16 + quad * 4;     // b*2048+n
                int bb = row >> 11, n = row & 2047;
                ushort4 o = {f2bf(acc[i][j][0]), f2bf(acc[i][j][1]),
                             f2bf(acc[i][j][2]), f2bf(acc[i][j][3])};
                *(ushort4*)&Vtg[((size_t)bb * INTER + col) * NN + n] = o;
            }
    }
}

// ---------------------------------------------------------------------------
// Out-projection: 2-term split-bf16 MFMA GEMM: out = ctx_h @ (W_h + W_l).
// ---------------------------------------------------------------------------
__global__ __launch_bounds__(256) void gemm_out2(
        const unsigned short* __restrict__ Ah,   // ctx bf16 [4096][1024]
        const unsigned short* __restrict__ Bh,   // W_out^T hi [1024][1024] bf16
        const unsigned short* __restrict__ Bl,   // W_out^T lo [1024][1024] bf16
        float* __restrict__ C) {                 // [4096][1024] fp32
    const int K = INTER, N = DIM;
    __shared__ __align__(16) unsigned short Ash[128][32];
    __shared__ __align__(16) unsigned short Bsh[64][32];
    __shared__ __align__(16) unsigned short Bsl[64][32];
    const int t = threadIdx.x;
    const int w = t >> 6, lane = t & 63, l15 = lane & 15, quad = lane >> 4;
    const int wr = w >> 1, wc = w & 1;           // 2x2 waves over 128x64
    const int row0 = blockIdx.y * 128, col0 = blockIdx.x * 64;
    const int lrow = lane >> 2, lkof = (lane & 3) * 8;

    f32x4 acc[4][2];
#pragma unroll
    for (int i = 0; i < 4; ++i)
#pragma unroll
        for (int j = 0; j < 2; ++j) acc[i][j] = (f32x4){0.f, 0.f, 0.f, 0.f};

    for (int k0 = 0; k0 < K; k0 += 32) {
#pragma unroll
        for (int c = 0; c < 2; ++c) {
            int rbase = w * 32 + c * 16;
            const unsigned short* gah = Ah + (size_t)(row0 + rbase + lrow) * K + k0 + lkof;
            __builtin_amdgcn_global_load_lds(
                (const __attribute__((address_space(1))) void*)gah,
                (__attribute__((address_space(3))) void*)&Ash[rbase][0], 16, 0, 0);
        }
        {
            int rbase = w * 16;
            const unsigned short* gbh = Bh + (size_t)(col0 + rbase + lrow) * K + k0 + lkof;
            const unsigned short* gbl = Bl + (size_t)(col0 + rbase + lrow) * K + k0 + lkof;
            __builtin_amdgcn_global_load_lds(
                (const __attribute__((address_space(1))) void*)gbh,
                (__attribute__((address_space(3))) void*)&Bsh[rbase][0], 16, 0, 0);
            __builtin_amdgcn_global_load_lds(
                (const __attribute__((address_space(1))) void*)gbl,
                (__attribute__((address_space(3))) void*)&Bsl[rbase][0], 16, 0, 0);
        }
        __syncthreads();
        bf16x8 ah[4], bh[2], bl[2];
#pragma unroll
        for (int i = 0; i < 4; ++i)
            ah[i] = *(const bf16x8*)&Ash[wr * 64 + i * 16 + l15][quad * 8];
#pragma unroll
        for (int j = 0; j < 2; ++j) {
            bh[j] = *(const bf16x8*)&Bsh[wc * 32 + j * 16 + l15][quad * 8];
            bl[j] = *(const bf16x8*)&Bsl[wc * 32 + j * 16 + l15][quad * 8];
        }
#pragma unroll
        for (int i = 0; i < 4; ++i)
#pragma unroll
            for (int j = 0; j < 2; ++j) {
                acc[i][j] = __builtin_amdgcn_mfma_f32_16x16x32_bf16(ah[i], bh[j], acc[i][j], 0, 0, 0);
                acc[i][j] = __builtin_amdgcn_mfma_f32_16x16x32_bf16(ah[i], bl[j], acc[i][j], 0, 0, 0);
            }
        __syncthreads();
    }
#pragma unroll
    for (int i = 0; i < 4; ++i)
#pragma unroll
        for (int j = 0; j < 2; ++j)
#pragma unroll
            for (int r = 0; r < 4; ++r)
                C[(size_t)(row0 + wr * 64 + i * 16 + quad * 4 + r) * N +
                  col0 + wc * 32 + j * 16 + l15] = acc[i][j][r];
}

// ---------------------------------------------------------------------------
// Segment-masked attention. Round-8 delta (math bit-identical to round 7):
//  - K/V staging via global_load_lds with PRE-SWIZZLED SOURCE (m173 trick):
//    LDS dest linear (key*64+dc = t*16B, lane-linear per wave), global col
//    pre-XORed -> LDS content identical to the manual swizzled store
//    (LDS[x^s]=G[x] <=> LDS[x]=G[x^s]). Read side untouched.
//  - Frees the 4 bf16x8 staging temporaries (~16 VGPR): natural VGPR ~84.
//    84 + 80 AGPR = 164 <= 512/3, so __launch_bounds__(256,3) -> 3 blocks/CU
//    (round 3's spill came from the manual-staging temps; gl_lds removes them).
//    SPILL WATCH: if FETCH jumps above ~74 MB or dur regresses, revert to (,2).
// ---------------------------------------------------------------------------
__global__ __launch_bounds__(256, 3) void attn_seg_mfma(
        const unsigned short* __restrict__ qk,    // bf16 [4096][2048] = q|k (q pre-scaled)
        const unsigned short* __restrict__ vtg,   // bf16 [2][1024][2048]
        const unsigned char* __restrict__ maskb,  // [B,N,N] bytes 0..3
        unsigned short* __restrict__ ctxh) {      // bf16 [4096][1024]
    __shared__ __align__(16) unsigned short KsL[2 * 4096];   // 16 KB, swizzled [key][64]
    __shared__ __align__(16) unsigned short VtL[2 * 4096];   // 16 KB, swizzled [dim][64]
    __shared__ __align__(16) unsigned char  MbL[2 * 5120];   // 10 KB, [row][80]
    __shared__ __align__(16) unsigned short El4[4 * 1024];   //  8 KB, swizzled, per-wave [i][64]

    const int t    = threadIdx.x;
    const int w    = t >> 6;
    const int lane = t & 63;
    const int l15  = lane & 15;
    const int quad = lane >> 4;
    const int ksw  = (l15 & 7) << 3;              // per-lane-constant swizzle XOR
    const int i0   = blockIdx.x * 64;
    const int hh   = blockIdx.y;
    const int b    = blockIdx.z;

    // ---- hoisted LDS offsets ----
    const int c0   = (quad * 8) ^ ksw;
    const int c1   = (32 + quad * 8) ^ ksw;
    const int a0   = l15 * 64 + c0;
    const int a1   = l15 * 64 + c1;
    const int wEl  = w * 1024;
    int ew[4];
#pragma unroll
    for (int nt = 0; nt < 4; ++nt) ew[nt] = l15 * 64 + ((nt * 16 + quad * 4) ^ ksw);
    const int ef0 = wEl + l15 * 64 + c0;
    const int ef1 = wEl + l15 * 64 + c1;
    const int mrd = (w * 16 + l15) * 80 + quad * 8;

    // ---- staging: linear LDS dest (t*8 shorts), pre-swizzled global source ----
    const int skey = t >> 3, sdc = (t & 7) * 8;
    const int ssw  = sdc ^ ((skey & 7) << 3);     // pre-swizzled source column
    const int sdst = t * 8;                       // linear LDS short offset (lane-linear)
    const unsigned short* pK0 = qk + (size_t)(b * NN + skey) * 2048 + 1024 + hh * HDIM + ssw;
    const unsigned short* pK1 = pK0 + (size_t)32 * 2048;
    const unsigned short* pV0 = vtg + ((size_t)b * INTER + hh * HDIM + skey) * NN + ssw;
    const unsigned short* pV1 = pV0 + (size_t)32 * NN;
    const unsigned char* pM = maskb + (size_t)(b * NN + i0 + (t >> 2)) * NN + (t & 3) * 16;
    const int wM = (t >> 2) * 80 + (t & 3) * 16;

    bf16x8 qa0, qa1;
    {
        const unsigned short* qp =
            qk + (size_t)(b * NN + i0 + w * 16 + l15) * 2048 + hh * HDIM + quad * 8;
        qa0 = *(const bf16x8*)qp;
        qa1 = *(const bf16x8*)(qp + 32);
    }

    bf16x8 onesb;
    {
        short ob = (l15 == 0) ? (short)0x3F80 : (short)0;
#pragma unroll
        for (int j = 0; j < 8; ++j) onesb[j] = ob;
    }

    f32x4 acc[NSEG][5];
#pragma unroll
    for (int m = 0; m < NSEG; ++m)
#pragma unroll
        for (int nt = 0; nt < 5; ++nt) acc[m][nt] = (f32x4){0.f, 0.f, 0.f, 0.f};

    auto stage = [&](int bb) {
        const int kb = (bb << 12) + sdst;
        __builtin_amdgcn_global_load_lds(
            (const __attribute__((address_space(1))) void*)pK0,
            (__attribute__((address_space(3))) void*)&KsL[kb], 16, 0, 0);
        __builtin_amdgcn_global_load_lds(
            (const __attribute__((address_space(1))) void*)pK1,
            (__attribute__((address_space(3))) void*)&KsL[kb + 2048], 16, 0, 0);
        __builtin_amdgcn_global_load_lds(
            (const __attribute__((address_space(1))) void*)pV0,
            (__attribute__((address_space(3))) void*)&VtL[kb], 16, 0, 0);
        __builtin_amdgcn_global_load_lds(
            (const __attribute__((address_space(1))) void*)pV1,
            (__attribute__((address_space(3))) void*)&VtL[kb + 2048], 16, 0, 0);
        *(uint4*)&MbL[bb * 5120 + wM] = *(const uint4*)pM;
        pK0 += (size_t)64 * 2048; pK1 += (size_t)64 * 2048;
        pV0 += 64; pV1 += 64;
        pM += 64;
    };

    stage(0);

    for (int jt = 0; jt < NN / 64; ++jt) {
        __syncthreads();                        // buf[jt&1] ready; buf[nxt] free
        if (jt + 1 < NN / 64) stage((jt + 1) & 1);
        const int bbase = (jt & 1) << 12;
        const int mbase = (jt & 1) * 5120;

        // ---- E = exp2(Q' K^T), swapped operands: D[j][i = w*16+l15] ----
#pragma unroll
        for (int nt = 0; nt < 4; ++nt) {
            f32x4 s = {0.f, 0.f, 0.f, 0.f};
            bf16x8 kb0 = *(const bf16x8*)&KsL[bbase + a0 + nt * 1024];
            bf16x8 kb1 = *(const bf16x8*)&KsL[bbase + a1 + nt * 1024];
            s = __builtin_amdgcn_mfma_f32_16x16x32_bf16(kb0, qa0, s, 0, 0, 0);
            s = __builtin_amdgcn_mfma_f32_16x16x32_bf16(kb1, qa1, s, 0, 0, 0);
            float e0 = __builtin_amdgcn_exp2f(s[0]);
            float e1 = __builtin_amdgcn_exp2f(s[1]);
            float e2 = __builtin_amdgcn_exp2f(s[2]);
            float e3 = __builtin_amdgcn_exp2f(s[3]);
            uint2 pk;
            pk.x = pack_bf16_rn(e0, e1);
            pk.y = pack_bf16_rn(e2, e3);
            *(uint2*)&El4[wEl + ew[nt]] = pk;   // El[i_local=l15][j..j+3]
        }

        // ---- PV: masked A variants x (4 dim tiles + ones tile) ----
#pragma unroll
        for (int ks = 0; ks < 2; ++ks) {
            union { int4 i; bf16x8 v; } ef;
            ef.i = *(const int4*)&El4[ks ? ef1 : ef0];
            uint2 sbv = *(const uint2*)&MbL[mbase + mrd + ks * 32];
            unsigned int dup[4];
            dup[0] = __builtin_amdgcn_perm(0u, sbv.x, 0x01010000u);
            dup[1] = __builtin_amdgcn_perm(0u, sbv.x, 0x03030202u);
            dup[2] = __builtin_amdgcn_perm(0u, sbv.y, 0x01010000u);
            dup[3] = __builtin_amdgcn_perm(0u, sbv.y, 0x03030202u);
            const unsigned int* ed = (const unsigned int*)&ef.i;
            bf16x8 vb[4];
#pragma unroll
            for (int nt = 0; nt < 4; ++nt)
                vb[nt] = *(const bf16x8*)&VtL[bbase + (ks ? a1 : a0) + nt * 1024];
            __builtin_amdgcn_s_setprio(1);
#pragma unroll
            for (int m = 0; m < NSEG; ++m) {
                const unsigned int Tm = 0xFFu << (8 * m);
                union { int4 i; bf16x8 v; } wm;
#pragma unroll
                for (int d = 0; d < 4; ++d)
                    ((unsigned int*)&wm.i)[d] = ed[d] & __builtin_amdgcn_perm(0u, Tm, dup[d]);
#pragma unroll
                for (int nt = 0; nt < 4; ++nt)
                    acc[m][nt] = __builtin_amdgcn_mfma_f32_16x16x32_bf16(wm.v, vb[nt], acc[m][nt], 0, 0, 0);
                acc[m][4] = __builtin_amdgcn_mfma_f32_16x16x32_bf16(wm.v, onesb, acc[m][4], 0, 0, 0);
            }
            __builtin_amdgcn_s_setprio(0);
        }
    }

    float rres[NSEG][4];
#pragma unroll
    for (int m = 0; m < NSEG; ++m)
#pragma unroll
        for (int r = 0; r < 4; ++r) {
            float sum = __shfl(acc[m][4][r], lane & 48, 64);
            rres[m][r] = (sum > 0.f) ? (1.f / sum) : 0.f;
        }
#pragma unroll
    for (int nt = 0; nt < 4; ++nt)
#pragma unroll
        for (int r = 0; r < 4; ++r) {
            float v = acc[0][nt][r] * rres[0][r] + acc[1][nt][r] * rres[1][r] +
                      acc[2][nt][r] * rres[2][r] + acc[3][nt][r] * rres[3][r];
            size_t idx = (size_t)(b * NN + i0 + w * 16 + quad * 4 + r) * INTER +
                         hh * HDIM + nt * 16 + l15;
            ctxh[idx] = f2bf(v);
        }
}

// ---------------------------------------------------------------------------
extern "C" void kernel_launch(void* const* d_in, const int* in_sizes, int n_in,
                              void* d_out, int out_size, void* d_ws, size_t ws_size,
                              hipStream_t stream) {
    const float* features = (const float*)d_in[0];  // [B,N,DIM] fp32
    const int*   mask     = (const int*)d_in[1];    // [B,N,N]
    const float* W_qkv    = (const float*)d_in[2];  // [DIM, 3*INTER] fp32
    const float* W_out    = (const float*)d_in[3];  // [INTER, DIM] fp32
    float* out = (float*)d_out;                     // [B,N,DIM] fp32

    const int M = BB * NN;  // 4096
    char* ws = (char*)d_ws;
    unsigned short* qk2  = (unsigned short*)ws;                 // bf16 [4096][2048] 16.8 MB
    ws += (size_t)M * 2048 * 2;
    unsigned short* vtg  = (unsigned short*)ws;                 // bf16 [2][1024][2048] 8.4 MB
    ws += (size_t)BB * INTER * NN * 2;
    unsigned short* ctxh = (unsigned short*)ws;                 // bf16 [4096][1024] 8.4 MB
    ws += (size_t)M * INTER * 2;
    unsigned short* featb = (unsigned short*)ws;                // bf16 [4096][1024] 8.4 MB
    ws += (size_t)M * DIM * 2;
    unsigned short* wqt = (unsigned short*)ws;                  // bf16 [3072][1024] 6.3 MB
    ws += (size_t)QKVW * DIM * 2;
    unsigned char* maskb = (unsigned char*)ws;                  // u8 [2][2048][2048] 8.4 MB
    ws += (size_t)BB * NN * NN;
    unsigned short* woh = (unsigned short*)ws;                  // bf16 [1024][1024] 2.1 MB
    ws += (size_t)DIM * INTER * 2;
    unsigned short* wol = (unsigned short*)ws;                  // bf16 [1024][1024] 2.1 MB
    ws += (size_t)DIM * INTER * 2;

    dim3 blk(256);

    // 0) all prepasses in one launch
    prep_fused<<<dim3(7168), blk, 0, stream>>>(
        features, featb, mask, maskb, W_qkv, wqt, W_out, woh, wol);

    // 1) qkv projection: q|k -> qk2 (q pre-scaled), v -> vtg (transposed per head)
    gemm_qkv_mfma<<<dim3(QKVW / 128, M / 128), blk, 0, stream>>>(featb, wqt, qk2, vtg);

    // 2) segment-masked attention -> ctx (bf16)
    attn_seg_mfma<<<dim3(NN / 64, NHEAD, BB), blk, 0, stream>>>(qk2, vtg, maskb, ctxh);

    // 3) out = ctx @ (W_h + W_l), 2-term split-bf16 MFMA
    gemm_out2<<<dim3(DIM / 64, M / 128), blk, 0, stream>>>(
        ctxh, woh, wol, out);
}

// Round 10
// 253.350 us; speedup vs baseline: 1.0243x; 1.0243x over previous
//
#include <hip/hip_runtime.h>
#include <hip/hip_bf16.h>

// Problem constants (reference: B=2, N=2048, DIM=1024, INTER=1024, HEAD=16, N_SEG=4)
#define BB 2
#define NN 2048
#define DIM 1024
#define INTER 1024
#define NHEAD 16
#define HDIM 64          // INTER / NHEAD
#define NSEG 4
#define QKVW (3 * INTER) // 3072

typedef __attribute__((ext_vector_type(8))) short bf16x8;
typedef __attribute__((ext_vector_type(4))) float f32x4;

static __device__ __forceinline__ unsigned short f2bf(float f) {
    __hip_bfloat16 h = __float2bfloat16(f);   // RNE
    return *reinterpret_cast<unsigned short*>(&h);
}
static __device__ __forceinline__ float bf2f(unsigned short u) {
    unsigned int x = ((unsigned int)u) << 16;
    return __builtin_bit_cast(float, x);
}
// Round-half-up bf16 pack: u+0x8000 then take hi16 of each via one v_perm.
// (v_cvt_pk_bf16_f32 was tried round 1: wrong semantics -> 6e-3 error.)
static __device__ __forceinline__ unsigned int pack_bf16_rn(float lo, float hi) {
    unsigned int u = __builtin_bit_cast(unsigned int, lo) + 0x8000u;
    unsigned int v = __builtin_bit_cast(unsigned int, hi) + 0x8000u;
    return __builtin_amdgcn_perm(v, u, 0x07060302u);
}

// ---------------------------------------------------------------------------
// Fused prepass (single launch):
//   blocks [0,4096)        : features fp32 -> bf16
//   blocks [4096,6144)     : mask int32 -> byte-packed
//   blocks [6144,6912)     : W_qkv  [1024][3072] fp32 -> wqt [3072][1024] bf16
//   blocks [6912,7168)     : W_out  [1024][1024] fp32 -> woh [1024][1024] bf16 T
// ---------------------------------------------------------------------------
__global__ __launch_bounds__(256) void prep_fused(
        const float* __restrict__ features, unsigned short* __restrict__ featb,
        const int* __restrict__ mask, unsigned char* __restrict__ maskb,
        const float* __restrict__ W_qkv, unsigned short* __restrict__ wqt,
        const float* __restrict__ W_out, unsigned short* __restrict__ woh) {
    __shared__ float tile[64][65];
    const int bid = blockIdx.x;
    const int t = threadIdx.x;

    if (bid < 4096) {                                   // ---- conv f32->bf16
        int i = (bid * 256 + t) * 4;
        float4 v = *(const float4*)&features[i];
        ushort4 o = {f2bf(v.x), f2bf(v.y), f2bf(v.z), f2bf(v.w)};
        *(ushort4*)&featb[i] = o;
        return;
    }
    if (bid < 6144) {                                   // ---- mask pack
        size_t i = (size_t)((bid - 4096) * 256 + t) * 16;
        int4 a = *(const int4*)&mask[i];
        int4 b = *(const int4*)&mask[i + 4];
        int4 c = *(const int4*)&mask[i + 8];
        int4 d = *(const int4*)&mask[i + 12];
        uint4 p;
        p.x = (unsigned)(a.x & 3) | ((unsigned)(a.y & 3) << 8) | ((unsigned)(a.z & 3) << 16) | ((unsigned)(a.w & 3) << 24);
        p.y = (unsigned)(b.x & 3) | ((unsigned)(b.y & 3) << 8) | ((unsigned)(b.z & 3) << 16) | ((unsigned)(b.w & 3) << 24);
        p.z = (unsigned)(c.x & 3) | ((unsigned)(c.y & 3) << 8) | ((unsigned)(c.z & 3) << 16) | ((unsigned)(c.w & 3) << 24);
        p.w = (unsigned)(d.x & 3) | ((unsigned)(d.y & 3) << 8) | ((unsigned)(d.z & 3) << 16) | ((unsigned)(d.w & 3) << 24);
        *(uint4*)&maskb[i] = p;
        return;
    }
    // ---- weight transposes (convert fp32 -> bf16, [R][C] -> [C][R]) ----
    const float* src;
    unsigned short* dst;
    int R, C, c0, r0;
    if (bid < 6912) {
        const int id = bid - 6144;
        src = W_qkv; dst = wqt; R = DIM; C = QKVW;
        c0 = (id % 48) * 64; r0 = (id / 48) * 64;
    } else {
        const int id = bid - 6912;
        src = W_out; dst = woh; R = INTER; C = DIM;
        c0 = (id % 16) * 64; r0 = (id / 16) * 64;
    }
#pragma unroll
    for (int it = 0; it < 4; ++it) {
        int r = it * 16 + (t >> 4);
        int c = (t & 15) * 4;
        float4 v = *(const float4*)&src[(size_t)(r0 + r) * C + c0 + c];
        tile[r][c] = v.x; tile[r][c + 1] = v.y; tile[r][c + 2] = v.z; tile[r][c + 3] = v.w;
    }
    __syncthreads();
#pragma unroll
    for (int it = 0; it < 4; ++it) {
        int c = it * 16 + (t >> 4);
        int r = (t & 15) * 4;
        ushort4 o = {f2bf(tile[r][c]), f2bf(tile[r + 1][c]), f2bf(tile[r + 2][c]), f2bf(tile[r + 3][c])};
        *(ushort4*)&dst[(size_t)(c0 + c) * R + r0 + r] = o;
    }
}

// ---------------------------------------------------------------------------
// QKV GEMM, bf16 MFMA (m97 structure): [4096][1024] @ [3072][1024]^T.
// q pre-scaled by log2e/32 so attention's exp path is a bare exp2.
// ---------------------------------------------------------------------------
#define GBK 32

__global__ __launch_bounds__(256) void gemm_qkv_mfma(
        const unsigned short* __restrict__ A,    // [4096][1024] bf16
        const unsigned short* __restrict__ Bt,   // [3072][1024] bf16
        unsigned short* __restrict__ Cqk,        // [4096][2048] bf16 (q|k)
        unsigned short* __restrict__ Vtg) {      // [2][1024][2048] bf16
    const int K = 1024;
    __shared__ __align__(16) unsigned short As[128][GBK];
    __shared__ __align__(16) unsigned short Bs[128][GBK];
    const int t = threadIdx.x;
    const int w = t >> 6, lane = t & 63, l15 = lane & 15, quad = lane >> 4;
    const int wr = w >> 1, wc = w & 1;
    const int row0 = blockIdx.y * 128, col0 = blockIdx.x * 128;
    const int lrow = lane >> 2;
    const int lkof = (lane & 3) * 8;

    f32x4 acc[4][4];
#pragma unroll
    for (int i = 0; i < 4; ++i)
#pragma unroll
        for (int j = 0; j < 4; ++j) acc[i][j] = (f32x4){0.f, 0.f, 0.f, 0.f};

    for (int k0 = 0; k0 < K; k0 += GBK) {
#pragma unroll
        for (int c = 0; c < 2; ++c) {
            int rbase = w * 32 + c * 16;
            const unsigned short* ga = A  + (size_t)(row0 + rbase + lrow) * K + k0 + lkof;
            const unsigned short* gb = Bt + (size_t)(col0 + rbase + lrow) * K + k0 + lkof;
            __builtin_amdgcn_global_load_lds(
                (const __attribute__((address_space(1))) void*)ga,
                (__attribute__((address_space(3))) void*)&As[rbase][0], 16, 0, 0);
            __builtin_amdgcn_global_load_lds(
                (const __attribute__((address_space(1))) void*)gb,
                (__attribute__((address_space(3))) void*)&Bs[rbase][0], 16, 0, 0);
        }
        __syncthreads();
        bf16x8 af[4], bfr[4];
#pragma unroll
        for (int i = 0; i < 4; ++i) af[i]  = *(const bf16x8*)&As[wr * 64 + i * 16 + l15][quad * 8];
#pragma unroll
        for (int j = 0; j < 4; ++j) bfr[j] = *(const bf16x8*)&Bs[wc * 64 + j * 16 + l15][quad * 8];
#pragma unroll
        for (int i = 0; i < 4; ++i)
#pragma unroll
            for (int j = 0; j < 4; ++j)
                acc[i][j] = __builtin_amdgcn_mfma_f32_16x16x32_bf16(af[i], bfr[j], acc[i][j], 0, 0, 0);
        __syncthreads();
    }

    if (col0 < 2048) {
        const float qs = (col0 < 1024) ? 0.04508422f : 1.0f;   // log2e/32 on q
#pragma unroll
        for (int i = 0; i < 4; ++i)
#pragma unroll
            for (int j = 0; j < 4; ++j)
#pragma unroll
                for (int r = 0; r < 4; ++r) {
                    int row = row0 + wr * 64 + i * 16 + quad * 4 + r;
                    int col = col0 + wc * 64 + j * 16 + l15;
                    Cqk[(size_t)row * 2048 + col] = f2bf(acc[i][j][r] * qs);
                }
    } else {
#pragma unroll
        for (int i = 0; i < 4; ++i)
#pragma unroll
            for (int j = 0; j < 4; ++j) {
                int col = col0 + wc * 64 + j * 16 + l15 - 2048;   // h*64+d
                int row = row0 + wr * 64 + i * 16 + quad * 4;     // b*2048+n
                int bb = row >> 11, n = row & 2047;
                ushort4 o = {f2bf(acc[i][j][0]), f2bf(acc[i][j][1]),
                             f2bf(acc[i][j][2]), f2bf(acc[i][j][3])};
                *(ushort4*)&Vtg[((size_t)bb * INTER + col) * NN + n] = o;
            }
    }
}

// ---------------------------------------------------------------------------
// Out-projection: plain bf16 MFMA GEMM: out = ctx @ W^T(bf16).
// (W-lo term dropped this round: bf16(W) error ~4e-5/elem propagates to
//  ~2e-5 in out — 50x under the E-path's 9.8e-4 absmax. ctx-lo was dropped
//  round 7 by the same analysis, verified.)
// ---------------------------------------------------------------------------
__global__ __launch_bounds__(256) void gemm_out1(
        const unsigned short* __restrict__ Ah,   // ctx bf16 [4096][1024]
        const unsigned short* __restrict__ Bh,   // W_out^T bf16 [1024][1024]
        float* __restrict__ C) {                 // [4096][1024] fp32
    const int K = INTER, N = DIM;
    __shared__ __align__(16) unsigned short Ash[128][32];
    __shared__ __align__(16) unsigned short Bsh[64][32];
    const int t = threadIdx.x;
    const int w = t >> 6, lane = t & 63, l15 = lane & 15, quad = lane >> 4;
    const int wr = w >> 1, wc = w & 1;           // 2x2 waves over 128x64
    const int row0 = blockIdx.y * 128, col0 = blockIdx.x * 64;
    const int lrow = lane >> 2, lkof = (lane & 3) * 8;

    f32x4 acc[4][2];
#pragma unroll
    for (int i = 0; i < 4; ++i)
#pragma unroll
        for (int j = 0; j < 2; ++j) acc[i][j] = (f32x4){0.f, 0.f, 0.f, 0.f};

    for (int k0 = 0; k0 < K; k0 += 32) {
#pragma unroll
        for (int c = 0; c < 2; ++c) {
            int rbase = w * 32 + c * 16;
            const unsigned short* gah = Ah + (size_t)(row0 + rbase + lrow) * K + k0 + lkof;
            __builtin_amdgcn_global_load_lds(
                (const __attribute__((address_space(1))) void*)gah,
                (__attribute__((address_space(3))) void*)&Ash[rbase][0], 16, 0, 0);
        }
        {
            int rbase = w * 16;
            const unsigned short* gbh = Bh + (size_t)(col0 + rbase + lrow) * K + k0 + lkof;
            __builtin_amdgcn_global_load_lds(
                (const __attribute__((address_space(1))) void*)gbh,
                (__attribute__((address_space(3))) void*)&Bsh[rbase][0], 16, 0, 0);
        }
        __syncthreads();
        bf16x8 ah[4], bh[2];
#pragma unroll
        for (int i = 0; i < 4; ++i)
            ah[i] = *(const bf16x8*)&Ash[wr * 64 + i * 16 + l15][quad * 8];
#pragma unroll
        for (int j = 0; j < 2; ++j)
            bh[j] = *(const bf16x8*)&Bsh[wc * 32 + j * 16 + l15][quad * 8];
#pragma unroll
        for (int i = 0; i < 4; ++i)
#pragma unroll
            for (int j = 0; j < 2; ++j)
                acc[i][j] = __builtin_amdgcn_mfma_f32_16x16x32_bf16(ah[i], bh[j], acc[i][j], 0, 0, 0);
        __syncthreads();
    }
#pragma unroll
    for (int i = 0; i < 4; ++i)
#pragma unroll
        for (int j = 0; j < 2; ++j)
#pragma unroll
            for (int r = 0; r < 4; ++r)
                C[(size_t)(row0 + wr * 64 + i * 16 + quad * 4 + r) * N +
                  col0 + wc * 32 + j * 16 + l15] = acc[i][j][r];
}

// ---------------------------------------------------------------------------
// Segment-masked attention. Round-10 delta:
//  - m=3 masked-PV variant replaced by FULL-E MFMAs (segments partition j,
//    so Sum_m E_masked = E). acc[3] = full-E PV and full-E denominator;
//    epilogue reconstructs: den3 = denF - den0 - den1 - den2 and
//    out = Sum_{m<3} acc_m (r_m - r3) + accF r3. Cuts 8 perm + 8 and + 2 dup
//    VALU per jt (~14% of the binding VALU pipe). Reconstruction noise is
//    ulp-level on den ~ 512 (each segment ~512 members under random mask).
// ---------------------------------------------------------------------------
__global__ __launch_bounds__(256, 3) void attn_seg_mfma(
        const unsigned short* __restrict__ qk,    // bf16 [4096][2048] = q|k (q pre-scaled)
        const unsigned short* __restrict__ vtg,   // bf16 [2][1024][2048]
        const unsigned char* __restrict__ maskb,  // [B,N,N] bytes 0..3
        unsigned short* __restrict__ ctxh) {      // bf16 [4096][1024]
    __shared__ __align__(16) unsigned short KsL[2 * 4096];   // 16 KB, swizzled [key][64]
    __shared__ __align__(16) unsigned short VtL[2 * 4096];   // 16 KB, swizzled [dim][64]
    __shared__ __align__(16) unsigned char  MbL[2 * 5120];   // 10 KB, [row][80]
    __shared__ __align__(16) unsigned short El4[4 * 1024];   //  8 KB, swizzled, per-wave [i][64]

    const int t    = threadIdx.x;
    const int w    = t >> 6;
    const int lane = t & 63;
    const int l15  = lane & 15;
    const int quad = lane >> 4;
    const int ksw  = (l15 & 7) << 3;              // per-lane-constant swizzle XOR
    const int i0   = blockIdx.x * 64;
    const int hh   = blockIdx.y;
    const int b    = blockIdx.z;

    // ---- hoisted LDS offsets ----
    const int c0   = (quad * 8) ^ ksw;
    const int c1   = (32 + quad * 8) ^ ksw;
    const int a0   = l15 * 64 + c0;
    const int a1   = l15 * 64 + c1;
    const int wEl  = w * 1024;
    int ew[4];
#pragma unroll
    for (int nt = 0; nt < 4; ++nt) ew[nt] = l15 * 64 + ((nt * 16 + quad * 4) ^ ksw);
    const int ef0 = wEl + l15 * 64 + c0;
    const int ef1 = wEl + l15 * 64 + c1;
    const int mrd = (w * 16 + l15) * 80 + quad * 8;

    // ---- staging: linear LDS dest (t*8 shorts), pre-swizzled global source ----
    const int skey = t >> 3, sdc = (t & 7) * 8;
    const int ssw  = sdc ^ ((skey & 7) << 3);     // pre-swizzled source column
    const int sdst = t * 8;                       // linear LDS short offset (lane-linear)
    const unsigned short* pK0 = qk + (size_t)(b * NN + skey) * 2048 + 1024 + hh * HDIM + ssw;
    const unsigned short* pK1 = pK0 + (size_t)32 * 2048;
    const unsigned short* pV0 = vtg + ((size_t)b * INTER + hh * HDIM + skey) * NN + ssw;
    const unsigned short* pV1 = pV0 + (size_t)32 * NN;
    const unsigned char* pM = maskb + (size_t)(b * NN + i0 + (t >> 2)) * NN + (t & 3) * 16;
    const int wM = (t >> 2) * 80 + (t & 3) * 16;

    bf16x8 qa0, qa1;
    {
        const unsigned short* qp =
            qk + (size_t)(b * NN + i0 + w * 16 + l15) * 2048 + hh * HDIM + quad * 8;
        qa0 = *(const bf16x8*)qp;
        qa1 = *(const bf16x8*)(qp + 32);
    }

    bf16x8 onesb;
    {
        short ob = (l15 == 0) ? (short)0x3F80 : (short)0;
#pragma unroll
        for (int j = 0; j < 8; ++j) onesb[j] = ob;
    }

    f32x4 acc[NSEG][5];
#pragma unroll
    for (int m = 0; m < NSEG; ++m)
#pragma unroll
        for (int nt = 0; nt < 5; ++nt) acc[m][nt] = (f32x4){0.f, 0.f, 0.f, 0.f};

    auto stage = [&](int bb) {
        const int kb = (bb << 12) + sdst;
        __builtin_amdgcn_global_load_lds(
            (const __attribute__((address_space(1))) void*)pK0,
            (__attribute__((address_space(3))) void*)&KsL[kb], 16, 0, 0);
        __builtin_amdgcn_global_load_lds(
            (const __attribute__((address_space(1))) void*)pK1,
            (__attribute__((address_space(3))) void*)&KsL[kb + 2048], 16, 0, 0);
        __builtin_amdgcn_global_load_lds(
            (const __attribute__((address_space(1))) void*)pV0,
            (__attribute__((address_space(3))) void*)&VtL[kb], 16, 0, 0);
        __builtin_amdgcn_global_load_lds(
            (const __attribute__((address_space(1))) void*)pV1,
            (__attribute__((address_space(3))) void*)&VtL[kb + 2048], 16, 0, 0);
        *(uint4*)&MbL[bb * 5120 + wM] = *(const uint4*)pM;
        pK0 += (size_t)64 * 2048; pK1 += (size_t)64 * 2048;
        pV0 += 64; pV1 += 64;
        pM += 64;
    };

    stage(0);

    for (int jt = 0; jt < NN / 64; ++jt) {
        __syncthreads();                        // buf[jt&1] ready; buf[nxt] free
        if (jt + 1 < NN / 64) stage((jt + 1) & 1);
        const int bbase = (jt & 1) << 12;
        const int mbase = (jt & 1) * 5120;

        // ---- E = exp2(Q' K^T), swapped operands: D[j][i = w*16+l15] ----
#pragma unroll
        for (int nt = 0; nt < 4; ++nt) {
            f32x4 s = {0.f, 0.f, 0.f, 0.f};
            bf16x8 kb0 = *(const bf16x8*)&KsL[bbase + a0 + nt * 1024];
            bf16x8 kb1 = *(const bf16x8*)&KsL[bbase + a1 + nt * 1024];
            s = __builtin_amdgcn_mfma_f32_16x16x32_bf16(kb0, qa0, s, 0, 0, 0);
            s = __builtin_amdgcn_mfma_f32_16x16x32_bf16(kb1, qa1, s, 0, 0, 0);
            float e0 = __builtin_amdgcn_exp2f(s[0]);
            float e1 = __builtin_amdgcn_exp2f(s[1]);
            float e2 = __builtin_amdgcn_exp2f(s[2]);
            float e3 = __builtin_amdgcn_exp2f(s[3]);
            uint2 pk;
            pk.x = pack_bf16_rn(e0, e1);
            pk.y = pack_bf16_rn(e2, e3);
            *(uint2*)&El4[wEl + ew[nt]] = pk;   // El[i_local=l15][j..j+3]
        }

        // ---- PV: 3 masked A variants + 1 full-E variant (x 4 dim + ones) ----
#pragma unroll
        for (int ks = 0; ks < 2; ++ks) {
            union { int4 i; bf16x8 v; } ef;
            ef.i = *(const int4*)&El4[ks ? ef1 : ef0];
            uint2 sbv = *(const uint2*)&MbL[mbase + mrd + ks * 32];
            unsigned int dup[4];
            dup[0] = __builtin_amdgcn_perm(0u, sbv.x, 0x01010000u);
            dup[1] = __builtin_amdgcn_perm(0u, sbv.x, 0x03030202u);
            dup[2] = __builtin_amdgcn_perm(0u, sbv.y, 0x01010000u);
            dup[3] = __builtin_amdgcn_perm(0u, sbv.y, 0x03030202u);
            const unsigned int* ed = (const unsigned int*)&ef.i;
            bf16x8 vb[4];
#pragma unroll
            for (int nt = 0; nt < 4; ++nt)
                vb[nt] = *(const bf16x8*)&VtL[bbase + (ks ? a1 : a0) + nt * 1024];
            __builtin_amdgcn_s_setprio(1);
#pragma unroll
            for (int m = 0; m < 3; ++m) {
                const unsigned int Tm = 0xFFu << (8 * m);
                union { int4 i; bf16x8 v; } wm;
#pragma unroll
                for (int d = 0; d < 4; ++d)
                    ((unsigned int*)&wm.i)[d] = ed[d] & __builtin_amdgcn_perm(0u, Tm, dup[d]);
#pragma unroll
                for (int nt = 0; nt < 4; ++nt)
                    acc[m][nt] = __builtin_amdgcn_mfma_f32_16x16x32_bf16(wm.v, vb[nt], acc[m][nt], 0, 0, 0);
                acc[m][4] = __builtin_amdgcn_mfma_f32_16x16x32_bf16(wm.v, onesb, acc[m][4], 0, 0, 0);
            }
            // m=3 slot: full (unmasked) E
#pragma unroll
            for (int nt = 0; nt < 4; ++nt)
                acc[3][nt] = __builtin_amdgcn_mfma_f32_16x16x32_bf16(ef.v, vb[nt], acc[3][nt], 0, 0, 0);
            acc[3][4] = __builtin_amdgcn_mfma_f32_16x16x32_bf16(ef.v, onesb, acc[3][4], 0, 0, 0);
            __builtin_amdgcn_s_setprio(0);
        }
    }

    // ---- epilogue: den3 = denF - den0 - den1 - den2; weights vs rres3 ----
    float rres[NSEG][4];
#pragma unroll
    for (int r = 0; r < 4; ++r) {
        float d0 = __shfl(acc[0][4][r], lane & 48, 64);
        float d1 = __shfl(acc[1][4][r], lane & 48, 64);
        float d2 = __shfl(acc[2][4][r], lane & 48, 64);
        float dF = __shfl(acc[3][4][r], lane & 48, 64);
        float d3 = dF - d0 - d1 - d2;
        float r3 = (d3 > 0.f) ? (1.f / d3) : 0.f;
        rres[3][r] = r3;
        rres[0][r] = ((d0 > 0.f) ? (1.f / d0) : 0.f) - r3;   // weight vs full-term
        rres[1][r] = ((d1 > 0.f) ? (1.f / d1) : 0.f) - r3;
        rres[2][r] = ((d2 > 0.f) ? (1.f / d2) : 0.f) - r3;
    }
#pragma unroll
    for (int nt = 0; nt < 4; ++nt)
#pragma unroll
        for (int r = 0; r < 4; ++r) {
            float v = acc[0][nt][r] * rres[0][r] + acc[1][nt][r] * rres[1][r] +
                      acc[2][nt][r] * rres[2][r] + acc[3][nt][r] * rres[3][r];
            size_t idx = (size_t)(b * NN + i0 + w * 16 + quad * 4 + r) * INTER +
                         hh * HDIM + nt * 16 + l15;
            ctxh[idx] = f2bf(v);
        }
}

// ---------------------------------------------------------------------------
extern "C" void kernel_launch(void* const* d_in, const int* in_sizes, int n_in,
                              void* d_out, int out_size, void* d_ws, size_t ws_size,
                              hipStream_t stream) {
    const float* features = (const float*)d_in[0];  // [B,N,DIM] fp32
    const int*   mask     = (const int*)d_in[1];    // [B,N,N]
    const float* W_qkv    = (const float*)d_in[2];  // [DIM, 3*INTER] fp32
    const float* W_out    = (const float*)d_in[3];  // [INTER, DIM] fp32
    float* out = (float*)d_out;                     // [B,N,DIM] fp32

    const int M = BB * NN;  // 4096
    char* ws = (char*)d_ws;
    unsigned short* qk2  = (unsigned short*)ws;                 // bf16 [4096][2048] 16.8 MB
    ws += (size_t)M * 2048 * 2;
    unsigned short* vtg  = (unsigned short*)ws;                 // bf16 [2][1024][2048] 8.4 MB
    ws += (size_t)BB * INTER * NN * 2;
    unsigned short* ctxh = (unsigned short*)ws;                 // bf16 [4096][1024] 8.4 MB
    ws += (size_t)M * INTER * 2;
    unsigned short* featb = (unsigned short*)ws;                // bf16 [4096][1024] 8.4 MB
    ws += (size_t)M * DIM * 2;
    unsigned short* wqt = (unsigned short*)ws;                  // bf16 [3072][1024] 6.3 MB
    ws += (size_t)QKVW * DIM * 2;
    unsigned char* maskb = (unsigned char*)ws;                  // u8 [2][2048][2048] 8.4 MB
    ws += (size_t)BB * NN * NN;
    unsigned short* woh = (unsigned short*)ws;                  // bf16 [1024][1024] 2.1 MB
    ws += (size_t)DIM * INTER * 2;

    dim3 blk(256);

    // 0) all prepasses in one launch
    prep_fused<<<dim3(7168), blk, 0, stream>>>(
        features, featb, mask, maskb, W_qkv, wqt, W_out, woh);

    // 1) qkv projection: q|k -> qk2 (q pre-scaled), v -> vtg (transposed per head)
    gemm_qkv_mfma<<<dim3(QKVW / 128, M / 128), blk, 0, stream>>>(featb, wqt, qk2, vtg);

    // 2) segment-masked attention -> ctx (bf16)
    attn_seg_mfma<<<dim3(NN / 64, NHEAD, BB), blk, 0, stream>>>(qk2, vtg, maskb, ctxh);

    // 3) out = ctx @ W^T, plain bf16 MFMA
    gemm_out1<<<dim3(DIM / 64, M / 128), blk, 0, stream>>>(
        ctxh, woh, out);
}

// Round 11
// 253.125 us; speedup vs baseline: 1.0252x; 1.0009x over previous
//
#include <hip/hip_runtime.h>
#include <hip/hip_bf16.h>

// Problem constants (reference: B=2, N=2048, DIM=1024, INTER=1024, HEAD=16, N_SEG=4)
#define BB 2
#define NN 2048
#define DIM 1024
#define INTER 1024
#define NHEAD 16
#define HDIM 64          // INTER / NHEAD
#define NSEG 4
#define QKVW (3 * INTER) // 3072

typedef __attribute__((ext_vector_type(8))) short bf16x8;
typedef __attribute__((ext_vector_type(4))) float f32x4;

static __device__ __forceinline__ unsigned short f2bf(float f) {
    __hip_bfloat16 h = __float2bfloat16(f);   // RNE
    return *reinterpret_cast<unsigned short*>(&h);
}
static __device__ __forceinline__ float bf2f(unsigned short u) {
    unsigned int x = ((unsigned int)u) << 16;
    return __builtin_bit_cast(float, x);
}
// Round-half-up bf16 pack: u+0x8000 then take hi16 of each via one v_perm.
// (v_cvt_pk_bf16_f32 was tried round 1: wrong semantics -> 6e-3 error.)
static __device__ __forceinline__ unsigned int pack_bf16_rn(float lo, float hi) {
    unsigned int u = __builtin_bit_cast(unsigned int, lo) + 0x8000u;
    unsigned int v = __builtin_bit_cast(unsigned int, hi) + 0x8000u;
    return __builtin_amdgcn_perm(v, u, 0x07060302u);
}

// ---------------------------------------------------------------------------
// Fused prepass (single launch):
//   blocks [0,4096)        : features fp32 -> bf16
//   blocks [4096,6144)     : mask int32 -> byte-packed
//   blocks [6144,6912)     : W_qkv  [1024][3072] fp32 -> wqt [3072][1024] bf16
//   blocks [6912,7168)     : W_out  [1024][1024] fp32 -> woh [1024][1024] bf16 T
// ---------------------------------------------------------------------------
__global__ __launch_bounds__(256) void prep_fused(
        const float* __restrict__ features, unsigned short* __restrict__ featb,
        const int* __restrict__ mask, unsigned char* __restrict__ maskb,
        const float* __restrict__ W_qkv, unsigned short* __restrict__ wqt,
        const float* __restrict__ W_out, unsigned short* __restrict__ woh) {
    __shared__ float tile[64][65];
    const int bid = blockIdx.x;
    const int t = threadIdx.x;

    if (bid < 4096) {                                   // ---- conv f32->bf16
        int i = (bid * 256 + t) * 4;
        float4 v = *(const float4*)&features[i];
        ushort4 o = {f2bf(v.x), f2bf(v.y), f2bf(v.z), f2bf(v.w)};
        *(ushort4*)&featb[i] = o;
        return;
    }
    if (bid < 6144) {                                   // ---- mask pack
        size_t i = (size_t)((bid - 4096) * 256 + t) * 16;
        int4 a = *(const int4*)&mask[i];
        int4 b = *(const int4*)&mask[i + 4];
        int4 c = *(const int4*)&mask[i + 8];
        int4 d = *(const int4*)&mask[i + 12];
        uint4 p;
        p.x = (unsigned)(a.x & 3) | ((unsigned)(a.y & 3) << 8) | ((unsigned)(a.z & 3) << 16) | ((unsigned)(a.w & 3) << 24);
        p.y = (unsigned)(b.x & 3) | ((unsigned)(b.y & 3) << 8) | ((unsigned)(b.z & 3) << 16) | ((unsigned)(b.w & 3) << 24);
        p.z = (unsigned)(c.x & 3) | ((unsigned)(c.y & 3) << 8) | ((unsigned)(c.z & 3) << 16) | ((unsigned)(c.w & 3) << 24);
        p.w = (unsigned)(d.x & 3) | ((unsigned)(d.y & 3) << 8) | ((unsigned)(d.z & 3) << 16) | ((unsigned)(d.w & 3) << 24);
        *(uint4*)&maskb[i] = p;
        return;
    }
    // ---- weight transposes (convert fp32 -> bf16, [R][C] -> [C][R]) ----
    const float* src;
    unsigned short* dst;
    int R, C, c0, r0;
    if (bid < 6912) {
        const int id = bid - 6144;
        src = W_qkv; dst = wqt; R = DIM; C = QKVW;
        c0 = (id % 48) * 64; r0 = (id / 48) * 64;
    } else {
        const int id = bid - 6912;
        src = W_out; dst = woh; R = INTER; C = DIM;
        c0 = (id % 16) * 64; r0 = (id / 16) * 64;
    }
#pragma unroll
    for (int it = 0; it < 4; ++it) {
        int r = it * 16 + (t >> 4);
        int c = (t & 15) * 4;
        float4 v = *(const float4*)&src[(size_t)(r0 + r) * C + c0 + c];
        tile[r][c] = v.x; tile[r][c + 1] = v.y; tile[r][c + 2] = v.z; tile[r][c + 3] = v.w;
    }
    __syncthreads();
#pragma unroll
    for (int it = 0; it < 4; ++it) {
        int c = it * 16 + (t >> 4);
        int r = (t & 15) * 4;
        ushort4 o = {f2bf(tile[r][c]), f2bf(tile[r + 1][c]), f2bf(tile[r + 2][c]), f2bf(tile[r + 3][c])};
        *(ushort4*)&dst[(size_t)(c0 + c) * R + r0 + r] = o;
    }
}

// ---------------------------------------------------------------------------
// QKV GEMM, bf16 MFMA (m97 structure): [4096][1024] @ [3072][1024]^T.
// q pre-scaled by log2e/32 so attention's exp path is a bare exp2.
// ---------------------------------------------------------------------------
#define GBK 32

__global__ __launch_bounds__(256) void gemm_qkv_mfma(
        const unsigned short* __restrict__ A,    // [4096][1024] bf16
        const unsigned short* __restrict__ Bt,   // [3072][1024] bf16
        unsigned short* __restrict__ Cqk,        // [4096][2048] bf16 (q|k)
        unsigned short* __restrict__ Vtg) {      // [2][1024][2048] bf16
    const int K = 1024;
    __shared__ __align__(16) unsigned short As[128][GBK];
    __shared__ __align__(16) unsigned short Bs[128][GBK];
    const int t = threadIdx.x;
    const int w = t >> 6, lane = t & 63, l15 = lane & 15, quad = lane >> 4;
    const int wr = w >> 1, wc = w & 1;
    const int row0 = blockIdx.y * 128, col0 = blockIdx.x * 128;
    const int lrow = lane >> 2;
    const int lkof = (lane & 3) * 8;

    f32x4 acc[4][4];
#pragma unroll
    for (int i = 0; i < 4; ++i)
#pragma unroll
        for (int j = 0; j < 4; ++j) acc[i][j] = (f32x4){0.f, 0.f, 0.f, 0.f};

    for (int k0 = 0; k0 < K; k0 += GBK) {
#pragma unroll
        for (int c = 0; c < 2; ++c) {
            int rbase = w * 32 + c * 16;
            const unsigned short* ga = A  + (size_t)(row0 + rbase + lrow) * K + k0 + lkof;
            const unsigned short* gb = Bt + (size_t)(col0 + rbase + lrow) * K + k0 + lkof;
            __builtin_amdgcn_global_load_lds(
                (const __attribute__((address_space(1))) void*)ga,
                (__attribute__((address_space(3))) void*)&As[rbase][0], 16, 0, 0);
            __builtin_amdgcn_global_load_lds(
                (const __attribute__((address_space(1))) void*)gb,
                (__attribute__((address_space(3))) void*)&Bs[rbase][0], 16, 0, 0);
        }
        __syncthreads();
        bf16x8 af[4], bfr[4];
#pragma unroll
        for (int i = 0; i < 4; ++i) af[i]  = *(const bf16x8*)&As[wr * 64 + i * 16 + l15][quad * 8];
#pragma unroll
        for (int j = 0; j < 4; ++j) bfr[j] = *(const bf16x8*)&Bs[wc * 64 + j * 16 + l15][quad * 8];
#pragma unroll
        for (int i = 0; i < 4; ++i)
#pragma unroll
            for (int j = 0; j < 4; ++j)
                acc[i][j] = __builtin_amdgcn_mfma_f32_16x16x32_bf16(af[i], bfr[j], acc[i][j], 0, 0, 0);
        __syncthreads();
    }

    if (col0 < 2048) {
        const float qs = (col0 < 1024) ? 0.04508422f : 1.0f;   // log2e/32 on q
#pragma unroll
        for (int i = 0; i < 4; ++i)
#pragma unroll
            for (int j = 0; j < 4; ++j)
#pragma unroll
                for (int r = 0; r < 4; ++r) {
                    int row = row0 + wr * 64 + i * 16 + quad * 4 + r;
                    int col = col0 + wc * 64 + j * 16 + l15;
                    Cqk[(size_t)row * 2048 + col] = f2bf(acc[i][j][r] * qs);
                }
    } else {
#pragma unroll
        for (int i = 0; i < 4; ++i)
#pragma unroll
            for (int j = 0; j < 4; ++j) {
                int col = col0 + wc * 64 + j * 16 + l15 - 2048;   // h*64+d
                int row = row0 + wr * 64 + i * 16 + quad * 4;     // b*2048+n
                int bb = row >> 11, n = row & 2047;
                ushort4 o = {f2bf(acc[i][j][0]), f2bf(acc[i][j][1]),
                             f2bf(acc[i][j][2]), f2bf(acc[i][j][3])};
                *(ushort4*)&Vtg[((size_t)bb * INTER + col) * NN + n] = o;
            }
    }
}

// ---------------------------------------------------------------------------
// Out-projection: plain bf16 MFMA GEMM: out = ctx @ W^T(bf16).
// (W-lo and ctx-lo terms dropped rounds 7/10 by error analysis; verified —
//  absmax pinned at 9.77e-4 across both changes.)
// ---------------------------------------------------------------------------
__global__ __launch_bounds__(256) void gemm_out1(
        const unsigned short* __restrict__ Ah,   // ctx bf16 [4096][1024]
        const unsigned short* __restrict__ Bh,   // W_out^T bf16 [1024][1024]
        float* __restrict__ C) {                 // [4096][1024] fp32
    const int K = INTER, N = DIM;
    __shared__ __align__(16) unsigned short Ash[128][32];
    __shared__ __align__(16) unsigned short Bsh[64][32];
    const int t = threadIdx.x;
    const int w = t >> 6, lane = t & 63, l15 = lane & 15, quad = lane >> 4;
    const int wr = w >> 1, wc = w & 1;           // 2x2 waves over 128x64
    const int row0 = blockIdx.y * 128, col0 = blockIdx.x * 64;
    const int lrow = lane >> 2, lkof = (lane & 3) * 8;

    f32x4 acc[4][2];
#pragma unroll
    for (int i = 0; i < 4; ++i)
#pragma unroll
        for (int j = 0; j < 2; ++j) acc[i][j] = (f32x4){0.f, 0.f, 0.f, 0.f};

    for (int k0 = 0; k0 < K; k0 += 32) {
#pragma unroll
        for (int c = 0; c < 2; ++c) {
            int rbase = w * 32 + c * 16;
            const unsigned short* gah = Ah + (size_t)(row0 + rbase + lrow) * K + k0 + lkof;
            __builtin_amdgcn_global_load_lds(
                (const __attribute__((address_space(1))) void*)gah,
                (__attribute__((address_space(3))) void*)&Ash[rbase][0], 16, 0, 0);
        }
        {
            int rbase = w * 16;
            const unsigned short* gbh = Bh + (size_t)(col0 + rbase + lrow) * K + k0 + lkof;
            __builtin_amdgcn_global_load_lds(
                (const __attribute__((address_space(1))) void*)gbh,
                (__attribute__((address_space(3))) void*)&Bsh[rbase][0], 16, 0, 0);
        }
        __syncthreads();
        bf16x8 ah[4], bh[2];
#pragma unroll
        for (int i = 0; i < 4; ++i)
            ah[i] = *(const bf16x8*)&Ash[wr * 64 + i * 16 + l15][quad * 8];
#pragma unroll
        for (int j = 0; j < 2; ++j)
            bh[j] = *(const bf16x8*)&Bsh[wc * 32 + j * 16 + l15][quad * 8];
#pragma unroll
        for (int i = 0; i < 4; ++i)
#pragma unroll
            for (int j = 0; j < 2; ++j)
                acc[i][j] = __builtin_amdgcn_mfma_f32_16x16x32_bf16(ah[i], bh[j], acc[i][j], 0, 0, 0);
        __syncthreads();
    }
#pragma unroll
    for (int i = 0; i < 4; ++i)
#pragma unroll
        for (int j = 0; j < 2; ++j)
#pragma unroll
            for (int r = 0; r < 4; ++r)
                C[(size_t)(row0 + wr * 64 + i * 16 + quad * 4 + r) * N +
                  col0 + wc * 32 + j * 16 + l15] = acc[i][j][r];
}

// ---------------------------------------------------------------------------
// Segment-masked attention. Round-11:
//  - PV REVERTED to round-9 4-masked-variant structure (round 10's full-E
//    m=3 slot regressed 111.4 -> 119.2 us: both pipes' busy% fell — the
//    masked-wm VALU interleave between MFMA clusters apparently aids
//    co-issue; full-E cluster created stalls).
//  - NEW: XCD-chunked block swizzle (T1). Grid flattened to 1D 1024;
//    w = (bid&7)*128 + (bid>>3) gives each XCD 128 consecutive logical
//    blocks = 4 complete (b,h) groups -> K/V (512 KB/group) and mask rows
//    concentrate in one XCD's L2. Bijective. Signature: FETCH 75.5 -> ~60 MB.
// ---------------------------------------------------------------------------
__global__ __launch_bounds__(256, 3) void attn_seg_mfma(
        const unsigned short* __restrict__ qk,    // bf16 [4096][2048] = q|k (q pre-scaled)
        const unsigned short* __restrict__ vtg,   // bf16 [2][1024][2048]
        const unsigned char* __restrict__ maskb,  // [B,N,N] bytes 0..3
        unsigned short* __restrict__ ctxh) {      // bf16 [4096][1024]
    __shared__ __align__(16) unsigned short KsL[2 * 4096];   // 16 KB, swizzled [key][64]
    __shared__ __align__(16) unsigned short VtL[2 * 4096];   // 16 KB, swizzled [dim][64]
    __shared__ __align__(16) unsigned char  MbL[2 * 5120];   // 10 KB, [row][80]
    __shared__ __align__(16) unsigned short El4[4 * 1024];   //  8 KB, swizzled, per-wave [i][64]

    const int t    = threadIdx.x;
    const int w    = t >> 6;
    const int lane = t & 63;
    const int l15  = lane & 15;
    const int quad = lane >> 4;
    const int ksw  = (l15 & 7) << 3;              // per-lane-constant swizzle XOR
    // XCD-chunk swizzle: physical XCD ~ blockIdx%8; give each XCD a
    // contiguous 128-logical-block chunk (= 4 whole (b,h) groups).
    const int bid  = blockIdx.x;
    const int wk   = ((bid & 7) << 7) + (bid >> 3);
    const int i0   = (wk & 31) * 64;
    const int hh   = (wk >> 5) & 15;
    const int b    = wk >> 9;

    // ---- hoisted LDS offsets ----
    const int c0   = (quad * 8) ^ ksw;
    const int c1   = (32 + quad * 8) ^ ksw;
    const int a0   = l15 * 64 + c0;
    const int a1   = l15 * 64 + c1;
    const int wEl  = w * 1024;
    int ew[4];
#pragma unroll
    for (int nt = 0; nt < 4; ++nt) ew[nt] = l15 * 64 + ((nt * 16 + quad * 4) ^ ksw);
    const int ef0 = wEl + l15 * 64 + c0;
    const int ef1 = wEl + l15 * 64 + c1;
    const int mrd = (w * 16 + l15) * 80 + quad * 8;

    // ---- staging: linear LDS dest (t*8 shorts), pre-swizzled global source ----
    const int skey = t >> 3, sdc = (t & 7) * 8;
    const int ssw  = sdc ^ ((skey & 7) << 3);     // pre-swizzled source column
    const int sdst = t * 8;                       // linear LDS short offset (lane-linear)
    const unsigned short* pK0 = qk + (size_t)(b * NN + skey) * 2048 + 1024 + hh * HDIM + ssw;
    const unsigned short* pK1 = pK0 + (size_t)32 * 2048;
    const unsigned short* pV0 = vtg + ((size_t)b * INTER + hh * HDIM + skey) * NN + ssw;
    const unsigned short* pV1 = pV0 + (size_t)32 * NN;
    const unsigned char* pM = maskb + (size_t)(b * NN + i0 + (t >> 2)) * NN + (t & 3) * 16;
    const int wM = (t >> 2) * 80 + (t & 3) * 16;

    bf16x8 qa0, qa1;
    {
        const unsigned short* qp =
            qk + (size_t)(b * NN + i0 + w * 16 + l15) * 2048 + hh * HDIM + quad * 8;
        qa0 = *(const bf16x8*)qp;
        qa1 = *(const bf16x8*)(qp + 32);
    }

    bf16x8 onesb;
    {
        short ob = (l15 == 0) ? (short)0x3F80 : (short)0;
#pragma unroll
        for (int j = 0; j < 8; ++j) onesb[j] = ob;
    }

    f32x4 acc[NSEG][5];
#pragma unroll
    for (int m = 0; m < NSEG; ++m)
#pragma unroll
        for (int nt = 0; nt < 5; ++nt) acc[m][nt] = (f32x4){0.f, 0.f, 0.f, 0.f};

    auto stage = [&](int bb) {
        const int kb = (bb << 12) + sdst;
        __builtin_amdgcn_global_load_lds(
            (const __attribute__((address_space(1))) void*)pK0,
            (__attribute__((address_space(3))) void*)&KsL[kb], 16, 0, 0);
        __builtin_amdgcn_global_load_lds(
            (const __attribute__((address_space(1))) void*)pK1,
            (__attribute__((address_space(3))) void*)&KsL[kb + 2048], 16, 0, 0);
        __builtin_amdgcn_global_load_lds(
            (const __attribute__((address_space(1))) void*)pV0,
            (__attribute__((address_space(3))) void*)&VtL[kb], 16, 0, 0);
        __builtin_amdgcn_global_load_lds(
            (const __attribute__((address_space(1))) void*)pV1,
            (__attribute__((address_space(3))) void*)&VtL[kb + 2048], 16, 0, 0);
        *(uint4*)&MbL[bb * 5120 + wM] = *(const uint4*)pM;
        pK0 += (size_t)64 * 2048; pK1 += (size_t)64 * 2048;
        pV0 += 64; pV1 += 64;
        pM += 64;
    };

    stage(0);

    for (int jt = 0; jt < NN / 64; ++jt) {
        __syncthreads();                        // buf[jt&1] ready; buf[nxt] free
        if (jt + 1 < NN / 64) stage((jt + 1) & 1);
        const int bbase = (jt & 1) << 12;
        const int mbase = (jt & 1) * 5120;

        // ---- E = exp2(Q' K^T), swapped operands: D[j][i = w*16+l15] ----
#pragma unroll
        for (int nt = 0; nt < 4; ++nt) {
            f32x4 s = {0.f, 0.f, 0.f, 0.f};
            bf16x8 kb0 = *(const bf16x8*)&KsL[bbase + a0 + nt * 1024];
            bf16x8 kb1 = *(const bf16x8*)&KsL[bbase + a1 + nt * 1024];
            s = __builtin_amdgcn_mfma_f32_16x16x32_bf16(kb0, qa0, s, 0, 0, 0);
            s = __builtin_amdgcn_mfma_f32_16x16x32_bf16(kb1, qa1, s, 0, 0, 0);
            float e0 = __builtin_amdgcn_exp2f(s[0]);
            float e1 = __builtin_amdgcn_exp2f(s[1]);
            float e2 = __builtin_amdgcn_exp2f(s[2]);
            float e3 = __builtin_amdgcn_exp2f(s[3]);
            uint2 pk;
            pk.x = pack_bf16_rn(e0, e1);
            pk.y = pack_bf16_rn(e2, e3);
            *(uint2*)&El4[wEl + ew[nt]] = pk;   // El[i_local=l15][j..j+3]
        }

        // ---- PV: masked A variants x (4 dim tiles + ones tile) ----
#pragma unroll
        for (int ks = 0; ks < 2; ++ks) {
            union { int4 i; bf16x8 v; } ef;
            ef.i = *(const int4*)&El4[ks ? ef1 : ef0];
            uint2 sbv = *(const uint2*)&MbL[mbase + mrd + ks * 32];
            unsigned int dup[4];
            dup[0] = __builtin_amdgcn_perm(0u, sbv.x, 0x01010000u);
            dup[1] = __builtin_amdgcn_perm(0u, sbv.x, 0x03030202u);
            dup[2] = __builtin_amdgcn_perm(0u, sbv.y, 0x01010000u);
            dup[3] = __builtin_amdgcn_perm(0u, sbv.y, 0x03030202u);
            const unsigned int* ed = (const unsigned int*)&ef.i;
            bf16x8 vb[4];
#pragma unroll
            for (int nt = 0; nt < 4; ++nt)
                vb[nt] = *(const bf16x8*)&VtL[bbase + (ks ? a1 : a0) + nt * 1024];
            __builtin_amdgcn_s_setprio(1);
#pragma unroll
            for (int m = 0; m < NSEG; ++m) {
                const unsigned int Tm = 0xFFu << (8 * m);
                union { int4 i; bf16x8 v; } wm;
#pragma unroll
                for (int d = 0; d < 4; ++d)
                    ((unsigned int*)&wm.i)[d] = ed[d] & __builtin_amdgcn_perm(0u, Tm, dup[d]);
#pragma unroll
                for (int nt = 0; nt < 4; ++nt)
                    acc[m][nt] = __builtin_amdgcn_mfma_f32_16x16x32_bf16(wm.v, vb[nt], acc[m][nt], 0, 0, 0);
                acc[m][4] = __builtin_amdgcn_mfma_f32_16x16x32_bf16(wm.v, onesb, acc[m][4], 0, 0, 0);
            }
            __builtin_amdgcn_s_setprio(0);
        }
    }

    float rres[NSEG][4];
#pragma unroll
    for (int m = 0; m < NSEG; ++m)
#pragma unroll
        for (int r = 0; r < 4; ++r) {
            float sum = __shfl(acc[m][4][r], lane & 48, 64);
            rres[m][r] = (sum > 0.f) ? (1.f / sum) : 0.f;
        }
#pragma unroll
    for (int nt = 0; nt < 4; ++nt)
#pragma unroll
        for (int r = 0; r < 4; ++r) {
            float v = acc[0][nt][r] * rres[0][r] + acc[1][nt][r] * rres[1][r] +
                      acc[2][nt][r] * rres[2][r] + acc[3][nt][r] * rres[3][r];
            size_t idx = (size_t)(b * NN + i0 + w * 16 + quad * 4 + r) * INTER +
                         hh * HDIM + nt * 16 + l15;
            ctxh[idx] = f2bf(v);
        }
}

// ---------------------------------------------------------------------------
extern "C" void kernel_launch(void* const* d_in, const int* in_sizes, int n_in,
                              void* d_out, int out_size, void* d_ws, size_t ws_size,
                              hipStream_t stream) {
    const float* features = (const float*)d_in[0];  // [B,N,DIM] fp32
    const int*   mask     = (const int*)d_in[1];    // [B,N,N]
    const float* W_qkv    = (const float*)d_in[2];  // [DIM, 3*INTER] fp32
    const float* W_out    = (const float*)d_in[3];  // [INTER, DIM] fp32
    float* out = (float*)d_out;                     // [B,N,DIM] fp32

    const int M = BB * NN;  // 4096
    char* ws = (char*)d_ws;
    unsigned short* qk2  = (unsigned short*)ws;                 // bf16 [4096][2048] 16.8 MB
    ws += (size_t)M * 2048 * 2;
    unsigned short* vtg  = (unsigned short*)ws;                 // bf16 [2][1024][2048] 8.4 MB
    ws += (size_t)BB * INTER * NN * 2;
    unsigned short* ctxh = (unsigned short*)ws;                 // bf16 [4096][1024] 8.4 MB
    ws += (size_t)M * INTER * 2;
    unsigned short* featb = (unsigned short*)ws;                // bf16 [4096][1024] 8.4 MB
    ws += (size_t)M * DIM * 2;
    unsigned short* wqt = (unsigned short*)ws;                  // bf16 [3072][1024] 6.3 MB
    ws += (size_t)QKVW * DIM * 2;
    unsigned char* maskb = (unsigned char*)ws;                  // u8 [2][2048][2048] 8.4 MB
    ws += (size_t)BB * NN * NN;
    unsigned short* woh = (unsigned short*)ws;                  // bf16 [1024][1024] 2.1 MB
    ws += (size_t)DIM * INTER * 2;

    dim3 blk(256);

    // 0) all prepasses in one launch
    prep_fused<<<dim3(7168), blk, 0, stream>>>(
        features, featb, mask, maskb, W_qkv, wqt, W_out, woh);

    // 1) qkv projection: q|k -> qk2 (q pre-scaled), v -> vtg (transposed per head)
    gemm_qkv_mfma<<<dim3(QKVW / 128, M / 128), blk, 0, stream>>>(featb, wqt, qk2, vtg);

    // 2) segment-masked attention -> ctx (bf16); 1D grid, XCD-chunk swizzled
    attn_seg_mfma<<<dim3(NN / 64 * NHEAD * BB), blk, 0, stream>>>(qk2, vtg, maskb, ctxh);

    // 3) out = ctx @ W^T, plain bf16 MFMA
    gemm_out1<<<dim3(DIM / 64, M / 128), blk, 0, stream>>>(
        ctxh, woh, out);
}